// Round 16
// baseline (247.109 us; speedup 1.0000x reference)
//
#include <hip/hip_runtime.h>
#include <math.h>

// GCN 2-layer + sigmoid head. CSR pull-gather, zero fp32 atomics.
// R30: delete the scan chain. fillbin flushes its LDS-sorted chunk DENSE at
//  the chunk base (fully coalesced full-line writes; the scattered-segment
//  write-amplification problem vanishes) + emits per-chunk bucket end-cursor
//  row Cend[c][nb]. k_tr transposes to CendT[b][c] (coalesced reads for
//  sort). k_sort2 (block = bucket) gathers its 782 small segments from the
//  dense chunks in two passes (count, scatter; 2nd pass L2-resident).
//  Deletes k_fb1 (dup 25.6MB read + 6.4M LDS atomics), k_scan1, k_scan2.
//  Lessons kept: gathers pinned ~50us across 7 variants (per-CU random-line
//  request floor, sc0 L1-bypass kept); no nt stores (R22); no global deg
//  atomics (R21); no LDS push (R20); no direct scatter (R18); no cross-XCD
//  plain-store handoff under coop sync (R28). All handoff via kernel bounds.
//   k_fillbin: LDS chunk counting-sort -> dense binned + Cend row
//   k_tr:     tiled transpose Cend -> CendT
//   k_sort:   per-bucket 2-pass segment gather -> csr, rowptr/rowend, dinv, xdq
//   k_gat1/2: node-group gathers (16 lanes/node, sc0 L1-bypass payloads)

#define TPB 256
#define NBS 8
#define NBKT 256        // nodes per bucket
#define MAXB 1024       // max buckets (n <= 262144)
#define BPT (MAXB / TPB)
#define CHUNK 8192      // edges per fillbin block
#define EPT (CHUNK / TPB)
#define CAP 9216        // bucket region capacity (mean 8184 + ~11 sigma)
#define NWAVE (TPB / 64)

#if defined(__has_builtin)
#if __has_builtin(__builtin_amdgcn_make_buffer_rsrc) && \
    __has_builtin(__builtin_amdgcn_raw_buffer_load_b128)
#define HAVE_BUFLOAD 1
#endif
#endif

#ifdef HAVE_BUFLOAD
typedef unsigned int u32x4v __attribute__((ext_vector_type(4)));
typedef __amdgpu_buffer_rsrc_t rsrc_t;
__device__ __forceinline__ rsrc_t mkrs(const void* p, int bytes) {
    return __builtin_amdgcn_make_buffer_rsrc(const_cast<void*>(p),
                                             (short)0, bytes, 0x00020000);
}
__device__ __forceinline__ uint4 g16(rsrc_t rs, const uint4* tbl, int idx) {
    u32x4v v = __builtin_amdgcn_raw_buffer_load_b128(rs, idx * 16, 0, 1);
    uint4 q;
    q.x = v.x; q.y = v.y; q.z = v.z; q.w = v.w;
    return q;
}
#else
typedef int rsrc_t;
__device__ __forceinline__ rsrc_t mkrs(const void* p, int bytes) { return 0; }
__device__ __forceinline__ uint4 g16(rsrc_t rs, const uint4* tbl, int idx) {
    return tbl[idx];
}
#endif

__device__ __forceinline__ unsigned short f2bf(float f) {
    unsigned u = __float_as_uint(f);
    unsigned r = (u + 0x7FFFu + ((u >> 16) & 1u)) >> 16;  // RNE
    return (unsigned short)r;
}
__device__ __forceinline__ unsigned pk2(float a, float b) {
    return (unsigned)f2bf(a) | ((unsigned)f2bf(b) << 16);
}
#define BFLO(u) __uint_as_float((u) << 16)
#define BFHI(u) __uint_as_float((u) & 0xFFFF0000u)

// LDS counting-sort of the chunk; DENSE flush at chunk base (coalesced int4
// full lines); per-bucket end-cursor row -> Cend. word: ((d&255)<<18)|s
__global__ void __launch_bounds__(TPB) k_fillbin(
        const int* __restrict__ src, const int* __restrict__ dst,
        int* __restrict__ binned, int* __restrict__ Cend, int e, int nb) {
    __shared__ __align__(16) int stage[CHUNK];  // 32 KB, bucket-sorted words
    __shared__ int h[MAXB];                     // 4 KB, hist -> cursor -> end
    __shared__ int wsum[NWAVE];
    int t = threadIdx.x;
    int c0 = blockIdx.x * CHUNK;
    int csize = min(e - c0, CHUNK);
#pragma unroll
    for (int k = 0; k < BPT; k++) h[t * BPT + k] = 0;
    __syncthreads();
    int dreg[EPT], sreg[EPT];
    if (csize == CHUNK && ((((size_t)(const void*)(dst + c0)) & 15) == 0)
                       && ((((size_t)(const void*)(src + c0)) & 15) == 0)) {
        const int4* d4 = (const int4*)(dst + c0);
        const int4* s4 = (const int4*)(src + c0);
#pragma unroll
        for (int k = 0; k < EPT / 4; k++) {
            int4 d = d4[t + k * TPB];
            int4 s = s4[t + k * TPB];
            dreg[4 * k + 0] = d.x; sreg[4 * k + 0] = s.x;
            dreg[4 * k + 1] = d.y; sreg[4 * k + 1] = s.y;
            dreg[4 * k + 2] = d.z; sreg[4 * k + 2] = s.z;
            dreg[4 * k + 3] = d.w; sreg[4 * k + 3] = s.w;
            atomicAdd(&h[d.x >> NBS], 1);
            atomicAdd(&h[d.y >> NBS], 1);
            atomicAdd(&h[d.z >> NBS], 1);
            atomicAdd(&h[d.w >> NBS], 1);
        }
    } else {
#pragma unroll
        for (int k = 0; k < EPT; k++) {
            int idx = t + k * TPB;
            int d = (idx < csize) ? dst[c0 + idx] : -1;
            int s = (idx < csize) ? src[c0 + idx] : 0;
            dreg[k] = d;
            sreg[k] = s;
            if (d >= 0) atomicAdd(&h[d >> NBS], 1);
        }
    }
    __syncthreads();
    // per-thread local prefix over its BPT bins
    int loc[BPT], hreg[BPT];
    int ts = 0;
#pragma unroll
    for (int k = 0; k < BPT; k++) {
        hreg[k] = h[t * BPT + k];
        loc[k] = ts;
        ts += hreg[k];
    }
    // block-wide inclusive scan of ts: wave shfl scan + wave-sum combine
    int lane = t & 63, wid = t >> 6;
    int v = ts;
#pragma unroll
    for (int off = 1; off < 64; off <<= 1) {
        int u = __shfl_up(v, off);
        if (lane >= off) v += u;
    }
    if (lane == 63) wsum[wid] = v;
    __syncthreads();
    int pre = 0;
#pragma unroll
    for (int wq = 0; wq < NWAVE - 1; wq++)
        if (wid > wq) pre += wsum[wq];
    int tbase = pre + v - ts;  // exclusive prefix for this thread's first bin
#pragma unroll
    for (int k = 0; k < BPT; k++)
        h[t * BPT + k] = tbase + loc[k];  // stage cursor (own bins)
    __syncthreads();
    // LDS counting sort of the chunk (registers -> LDS only)
#pragma unroll
    for (int k = 0; k < EPT; k++) {
        int d = dreg[k];
        if (d >= 0) {
            int b = d >> NBS;
            int r = atomicAdd(&h[b], 1);
            stage[r] = ((d & (NBKT - 1)) << 18) | sreg[k];
        }
    }
    __syncthreads();
    // dense flush at chunk base (coalesced int4 + scalar tail)
    for (int kb = 4 * t; kb + 4 <= csize; kb += 4 * TPB) {
        int4 sv = *(const int4*)&stage[kb];
        *(int4*)&binned[c0 + kb] = sv;
    }
    for (int k = (csize & ~3) + t; k < csize; k += TPB)
        binned[c0 + k] = stage[k];
    // per-bucket end cursors (h[b] is now bucket b's end within the chunk)
    int* row = Cend + (size_t)blockIdx.x * nb;
    for (int b = t; b < nb; b += TPB) row[b] = h[b];
}

// tiled transpose: CendT[b][c] = Cend[c][b]  (nblk x nb -> nb x nblk)
#define TDIM 64
__global__ void __launch_bounds__(TPB) k_tr(
        const int* __restrict__ Cend, int* __restrict__ CendT,
        int nblk, int nb) {
    __shared__ int tile[TDIM][TDIM + 1];
    int tx = threadIdx.x & (TDIM - 1);
    int ty4 = threadIdx.x >> 6;          // 0..3
    int bx = blockIdx.x * TDIM;          // b dim
    int by = blockIdx.y * TDIM;          // c dim
    for (int j = ty4; j < TDIM; j += 4) {
        int c = by + j, b = bx + tx;
        tile[j][tx] = (c < nblk && b < nb) ? Cend[(size_t)c * nb + b] : 0;
    }
    __syncthreads();
    for (int j = ty4; j < TDIM; j += 4) {
        int b = bx + j, c = by + tx;
        if (b < nb && c < nblk) CendT[(size_t)b * nblk + c] = tile[tx][j];
    }
}

// per-bucket 2-pass segment gather + counting sort -> dense csr,
// rowptr/rowend, dinv, xdq(bf16). Segments from dense chunks via CendT.
__global__ void __launch_bounds__(TPB) k_sort(
        const int* __restrict__ binned, const int* __restrict__ CendT,
        const float* __restrict__ x, int* __restrict__ csr,
        int* __restrict__ rowptr, int* __restrict__ rowend,
        float* __restrict__ dinv, uint4* __restrict__ xdq, int n, int nblk) {
    __shared__ __align__(16) int stage[CAP];     // 36 KB
    __shared__ int cnt[NBKT];
    __shared__ int curs[NBKT];
    __shared__ int wsum[NWAVE];
    int b = blockIdx.x, t = threadIdx.x;
    int base = b * CAP;
    cnt[t] = 0;
    __syncthreads();
    const int* rowE = CendT + (size_t)b * nblk;
    const int* rowS = CendT + (size_t)(b > 0 ? b - 1 : 0) * nblk;
    // pass 1: count nodes (segments read; descriptor rows coalesced)
    for (int c = t; c < nblk; c += TPB) {
        int s0 = (b > 0) ? rowS[c] : 0;
        int s1 = rowE[c];
        const int* p = binned + (size_t)c * CHUNK;
        int k = s0;
        for (; k + 4 <= s1; k += 4) {
            int w0 = p[k], w1 = p[k + 1], w2 = p[k + 2], w3 = p[k + 3];
            atomicAdd(&cnt[w0 >> 18], 1);
            atomicAdd(&cnt[w1 >> 18], 1);
            atomicAdd(&cnt[w2 >> 18], 1);
            atomicAdd(&cnt[w3 >> 18], 1);
        }
        for (; k < s1; k++) atomicAdd(&cnt[p[k] >> 18], 1);
    }
    __syncthreads();
    // exclusive scan of 256 bins: wave shfl scan + combine (1 barrier)
    int v = cnt[t];
    int lane = t & 63, wid = t >> 6;
    int iv = v;
#pragma unroll
    for (int off = 1; off < 64; off <<= 1) {
        int u = __shfl_up(iv, off);
        if (lane >= off) iv += u;
    }
    if (lane == 63) wsum[wid] = iv;
    __syncthreads();
    int pre = 0;
#pragma unroll
    for (int wq = 0; wq < NWAVE - 1; wq++)
        if (wid > wq) pre += wsum[wq];
    int ex = pre + iv - v;  // exclusive
    curs[t] = ex;
    // per-node outputs
    int i = (b << NBS) + t;
    rowptr[i] = base + ex;
    rowend[i] = base + ex + v;
    if (i < n) {
        float di = rsqrtf((float)(v + 1));
        dinv[i] = di;
        uint4 q;
        q.x = pk2(x[i * 6 + 0] * di, x[i * 6 + 1] * di);
        q.y = pk2(x[i * 6 + 2] * di, x[i * 6 + 3] * di);
        q.z = pk2(x[i * 6 + 4] * di, x[i * 6 + 5] * di);
        q.w = 0;
        xdq[i] = q;
    }
    __syncthreads();
    // pass 2: scatter into LDS stage (segments now L2-resident)
    for (int c = t; c < nblk; c += TPB) {
        int s0 = (b > 0) ? rowS[c] : 0;
        int s1 = rowE[c];
        const int* p = binned + (size_t)c * CHUNK;
        int k = s0;
        for (; k + 4 <= s1; k += 4) {
            int w0 = p[k], w1 = p[k + 1], w2 = p[k + 2], w3 = p[k + 3];
            int r0 = atomicAdd(&curs[w0 >> 18], 1);
            int r1 = atomicAdd(&curs[w1 >> 18], 1);
            int r2 = atomicAdd(&curs[w2 >> 18], 1);
            int r3 = atomicAdd(&curs[w3 >> 18], 1);
            stage[r0] = w0 & 0x3FFFF;
            stage[r1] = w1 & 0x3FFFF;
            stage[r2] = w2 & 0x3FFFF;
            stage[r3] = w3 & 0x3FFFF;
        }
        for (; k < s1; k++) {
            int w = p[k];
            int r = atomicAdd(&curs[w >> 18], 1);
            stage[r] = w & 0x3FFFF;
        }
    }
    __syncthreads();
    // dense flush of valid entries
    int cv = curs[NBKT - 1];   // total valid entries in this bucket
    for (int kb = 4 * t; kb + 4 <= cv; kb += 4 * TPB) {
        int4 sv = *(const int4*)&stage[kb];
        *(int4*)&csr[base + kb] = sv;
    }
    for (int k = (cv & ~3) + t; k < cv; k += TPB)
        csr[base + k] = stage[k];
}

// layer-1 gather (pre-W1 domain, bf16 payload): 16 lanes/node, 4 nodes/wave.
// neighbor payloads via sc0 buffer loads (L1 bypass).
// epilogue: agg6 (incl self) -> @W1 -> relu(di*.+b1) -> @W2 -> *di -> g2q (bf16)
__global__ void __launch_bounds__(TPB) k_gat1(
        const uint4* __restrict__ xdq, const int* __restrict__ csr,
        const int* __restrict__ rowptr, const int* __restrict__ rowend,
        const float* __restrict__ dinv,
        const float* __restrict__ b1, const float* __restrict__ W1,
        const float* __restrict__ W2, uint2* __restrict__ g2q, int n, int np) {
    __shared__ float w1[96];   // 6 x 16
    __shared__ float w2[128];  // 16 x 8
    __shared__ float bb[16];
    if (threadIdx.x < 96) w1[threadIdx.x] = W1[threadIdx.x];
    if (threadIdx.x < 128) w2[threadIdx.x] = W2[threadIdx.x];
    if (threadIdx.x < 16) bb[threadIdx.x] = b1[threadIdx.x];
    __syncthreads();
    rsrc_t rs = mkrs(xdq, np * 16);
    int sub = threadIdx.x & 15;                    // lane within node group
    int i = blockIdx.x * 16 + (threadIdx.x >> 4);  // 16 nodes per block
    bool valid = (i < n);
    int r0 = rowptr[i], r1 = rowend[i];            // padded nodes: r0 == r1
    float a0 = 0.f, a1 = 0.f, a2 = 0.f, a3 = 0.f, a4 = 0.f, a5 = 0.f;
    float c0 = 0.f, c1 = 0.f, c2 = 0.f, c3 = 0.f, c4 = 0.f, c5 = 0.f;
    if (valid && sub == 0) {  // self-loop term
        uint4 q = xdq[i];
        a0 += BFLO(q.x); a1 += BFHI(q.x);
        a2 += BFLO(q.y); a3 += BFHI(q.y);
        a4 += BFLO(q.z); a5 += BFHI(q.z);
    }
    int j = r0 + sub;
    while (j + 16 < r1) {
        uint4 q = g16(rs, xdq, csr[j]);
        uint4 p = g16(rs, xdq, csr[j + 16]);
        a0 += BFLO(q.x); a1 += BFHI(q.x);
        a2 += BFLO(q.y); a3 += BFHI(q.y);
        a4 += BFLO(q.z); a5 += BFHI(q.z);
        c0 += BFLO(p.x); c1 += BFHI(p.x);
        c2 += BFLO(p.y); c3 += BFHI(p.y);
        c4 += BFLO(p.z); c5 += BFHI(p.z);
        j += 32;
    }
    if (j < r1) {
        uint4 q = g16(rs, xdq, csr[j]);
        a0 += BFLO(q.x); a1 += BFHI(q.x);
        a2 += BFLO(q.y); a3 += BFHI(q.y);
        a4 += BFLO(q.z); a5 += BFHI(q.z);
    }
    a0 += c0; a1 += c1; a2 += c2; a3 += c3; a4 += c4; a5 += c5;
#pragma unroll
    for (int m = 1; m <= 8; m <<= 1) {  // reduce within 16-lane node group
        a0 += __shfl_xor(a0, m); a1 += __shfl_xor(a1, m);
        a2 += __shfl_xor(a2, m); a3 += __shfl_xor(a3, m);
        a4 += __shfl_xor(a4, m); a5 += __shfl_xor(a5, m);
    }
    float di = valid ? dinv[i] : 0.f;
    int f = sub;  // lane = hidden feature
    float hf = a0 * w1[f] + a1 * w1[16 + f] + a2 * w1[32 + f]
             + a3 * w1[48 + f] + a4 * w1[64 + f] + a5 * w1[80 + f];
    float tf = fmaxf(di * hf + bb[f], 0.0f);
    float p0 = tf * w2[f * 8 + 0], p1 = tf * w2[f * 8 + 1];
    float p2 = tf * w2[f * 8 + 2], p3 = tf * w2[f * 8 + 3];
    float p4 = tf * w2[f * 8 + 4], p5 = tf * w2[f * 8 + 5];
    float p6 = tf * w2[f * 8 + 6], p7 = tf * w2[f * 8 + 7];
#pragma unroll
    for (int m = 1; m <= 8; m <<= 1) {  // reduce over the 16 f-lanes
        p0 += __shfl_xor(p0, m); p1 += __shfl_xor(p1, m);
        p2 += __shfl_xor(p2, m); p3 += __shfl_xor(p3, m);
        p4 += __shfl_xor(p4, m); p5 += __shfl_xor(p5, m);
        p6 += __shfl_xor(p6, m); p7 += __shfl_xor(p7, m);
    }
    if (valid && sub < 2) {
        float q0 = sub ? p4 : p0, q1 = sub ? p5 : p1;
        float q2 = sub ? p6 : p2, q3 = sub ? p7 : p3;
        uint2 o;
        o.x = pk2(q0 * di, q1 * di);
        o.y = pk2(q2 * di, q3 * di);
        g2q[i * 2 + sub] = o;
    }
}

// layer-2 gather (bf16 payload): 16 lanes/node, 4 nodes/wave, sc0 gathers.
// fused head: h = relu(dinv*agg8 + b2); out = sigmoid(h @ Wfc + bfc)
__global__ void __launch_bounds__(TPB) k_gat2(
        const uint4* __restrict__ g2q, const int* __restrict__ csr,
        const int* __restrict__ rowptr, const int* __restrict__ rowend,
        const float* __restrict__ dinv,
        const float* __restrict__ b2, const float* __restrict__ Wfc,
        const float* __restrict__ bfc, float* __restrict__ out, int n, int np) {
    __shared__ float w[8];
    __shared__ float bb[8];
    __shared__ float bf;
    if (threadIdx.x < 8) { w[threadIdx.x] = Wfc[threadIdx.x]; bb[threadIdx.x] = b2[threadIdx.x]; }
    if (threadIdx.x == 0) bf = bfc[0];
    __syncthreads();
    rsrc_t rs = mkrs(g2q, np * 16);
    int sub = threadIdx.x & 15;
    int i = blockIdx.x * 16 + (threadIdx.x >> 4);
    bool valid = (i < n);
    int r0 = rowptr[i], r1 = rowend[i];
    float a0 = 0.f, a1 = 0.f, a2 = 0.f, a3 = 0.f;
    float a4 = 0.f, a5 = 0.f, a6 = 0.f, a7 = 0.f;
    if (valid && sub == 0) {  // self-loop term
        uint4 q = g2q[i];
        a0 += BFLO(q.x); a1 += BFHI(q.x); a2 += BFLO(q.y); a3 += BFHI(q.y);
        a4 += BFLO(q.z); a5 += BFHI(q.z); a6 += BFLO(q.w); a7 += BFHI(q.w);
    }
    float c0 = 0.f, c1 = 0.f, c2 = 0.f, c3 = 0.f;
    float c4 = 0.f, c5 = 0.f, c6 = 0.f, c7 = 0.f;
    int j = r0 + sub;
    while (j + 16 < r1) {
        uint4 q = g16(rs, g2q, csr[j]);
        uint4 p = g16(rs, g2q, csr[j + 16]);
        a0 += BFLO(q.x); a1 += BFHI(q.x); a2 += BFLO(q.y); a3 += BFHI(q.y);
        a4 += BFLO(q.z); a5 += BFHI(q.z); a6 += BFLO(q.w); a7 += BFHI(q.w);
        c0 += BFLO(p.x); c1 += BFHI(p.x); c2 += BFLO(p.y); c3 += BFHI(p.y);
        c4 += BFLO(p.z); c5 += BFHI(p.z); c6 += BFLO(p.w); c7 += BFHI(p.w);
        j += 32;
    }
    if (j < r1) {
        uint4 q = g16(rs, g2q, csr[j]);
        a0 += BFLO(q.x); a1 += BFHI(q.x); a2 += BFLO(q.y); a3 += BFHI(q.y);
        a4 += BFLO(q.z); a5 += BFHI(q.z); a6 += BFLO(q.w); a7 += BFHI(q.w);
    }
    a0 += c0; a1 += c1; a2 += c2; a3 += c3;
    a4 += c4; a5 += c5; a6 += c6; a7 += c7;
#pragma unroll
    for (int m = 1; m <= 8; m <<= 1) {  // reduce within 16-lane node group
        a0 += __shfl_xor(a0, m); a1 += __shfl_xor(a1, m);
        a2 += __shfl_xor(a2, m); a3 += __shfl_xor(a3, m);
        a4 += __shfl_xor(a4, m); a5 += __shfl_xor(a5, m);
        a6 += __shfl_xor(a6, m); a7 += __shfl_xor(a7, m);
    }
    if (valid && sub == 0) {  // head computed once per node (cheap, no shfl)
        float di = dinv[i];
        float o = bf;
        o += fmaxf(di * a0 + bb[0], 0.0f) * w[0];
        o += fmaxf(di * a1 + bb[1], 0.0f) * w[1];
        o += fmaxf(di * a2 + bb[2], 0.0f) * w[2];
        o += fmaxf(di * a3 + bb[3], 0.0f) * w[3];
        o += fmaxf(di * a4 + bb[4], 0.0f) * w[4];
        o += fmaxf(di * a5 + bb[5], 0.0f) * w[5];
        o += fmaxf(di * a6 + bb[6], 0.0f) * w[6];
        o += fmaxf(di * a7 + bb[7], 0.0f) * w[7];
        out[i] = 1.0f / (1.0f + expf(-o));
    }
}

extern "C" void kernel_launch(void* const* d_in, const int* in_sizes, int n_in,
                              void* d_out, int out_size, void* d_ws, size_t ws_size,
                              hipStream_t stream) {
    const float* x   = (const float*)d_in[0];
    const int*   ei  = (const int*)d_in[1];
    const float* W1  = (const float*)d_in[2];
    const float* b1  = (const float*)d_in[3];
    const float* W2  = (const float*)d_in[4];
    const float* b2  = (const float*)d_in[5];
    const float* Wfc = (const float*)d_in[6];
    const float* bfc = (const float*)d_in[7];
    float* out = (float*)d_out;

    const int n = in_sizes[0] / 6;   // 200000 (<= 262144 for 18-bit packing)
    const int e = in_sizes[1] / 2;   // 6400000
    const int* src = ei;
    const int* dst = ei + e;
    const int nb = (n + NBKT - 1) >> NBS;  // 782 buckets
    const size_t np = (size_t)nb << NBS;   // padded node count (200192)
    const int nblk = (e + CHUNK - 1) / CHUNK;  // 782 chunks

    int* Cend   = (int*)d_ws;                    // nblk * nb
    int* CendT  = Cend + (size_t)nblk * nb;      // nb * nblk
    int* binned = CendT + (size_t)nb * nblk;     // nblk * CHUNK (dense chunks)
    int* csr    = binned + (size_t)nblk * CHUNK; // nb * CAP
    int* rowptr = csr + (size_t)nb * CAP;        // np
    int* rowend = rowptr + np;                   // np
    float* dinv = (float*)(rowend + np);         // np
    size_t off  = (size_t)((int*)(dinv + np) - (int*)d_ws);
    off = (off + 3) & ~(size_t)3;                // 16B-align the uint4 arrays
    uint4* xdq  = (uint4*)((int*)d_ws + off);    // np * 16 B
    uint2* g2q  = (uint2*)(xdq + np);            // np * 16 B

    int gw = (n + 15) / 16;              // node-group blocks (16 nodes/block)
    int npw = (int)np;
    dim3 trg((nb + TDIM - 1) / TDIM, (nblk + TDIM - 1) / TDIM);

    k_fillbin<<<nblk, TPB, 0, stream>>>(src, dst, binned, Cend, e, nb);
    k_tr<<<trg, TPB, 0, stream>>>(Cend, CendT, nblk, nb);
    k_sort<<<nb, TPB, 0, stream>>>(binned, CendT, x, csr, rowptr, rowend,
                                   dinv, xdq, n, nblk);
    k_gat1<<<gw, TPB, 0, stream>>>(xdq, csr, rowptr, rowend, dinv, b1, W1, W2,
                                   (uint2*)g2q, n, npw);
    k_gat2<<<gw, TPB, 0, stream>>>((const uint4*)g2q, csr, rowptr, rowend, dinv,
                                   b2, Wfc, bfc, out, n, npw);
}

// Round 17
// 229.935 us; speedup vs baseline: 1.0747x; 1.0747x over previous
//
#include <hip/hip_runtime.h>
#include <math.h>

// GCN 2-layer + sigmoid head. CSR pull-gather, zero fp32 atomics.
// R31 = R29 exact revert (231.0us verified optimum; R30's dense+gather-sort
//  regressed to 247 via 114MB two-pass segment-read amplification).
//  Session lessons encoded in this structure:
//   - staged binning mandatory (R18 direct scatter: 393MB write-alloc ampl)
//   - deterministic offsets, no contended returning atomics (R16/R17)
//   - no LDS fp32 push (R20: 51M ds_add = DS-pipe saturation, 339us/layer)
//   - no global deg atomics (R21: 204MB coherence traffic)
//   - no nt hints on scattered stores (R22: defeats L2 write-combining)
//   - gathers at per-CU random-request floor (~4.8cy/edge, 7 variants)
//   - no cross-XCD plain-store handoff under coop grid.sync (R28)
//   - scattered staged WRITES beat scattered two-pass READS (R30)
//   k_fb1:   per-chunk bucket histogram -> C[chunk][nb]
//   k_scan1/2: 2-level deterministic offset scan (4-rounded counts)
//   k_fillbin: LDS chunk counting-sort (counts from C) -> aligned binned
//   k_sort:  bucket counting sort -> dense csr, rowptr/rowend, dinv, xdq
//   k_gat1/2: node-group gathers (16 lanes/node, sc0 L1-bypass payloads)

#define TPB 256
#define NBS 8
#define NBKT 256        // nodes per bucket
#define MAXB 1024       // max buckets (n <= 262144)
#define BPT (MAXB / TPB)
#define CHUNK 8192      // edges per fillbin block
#define EPT (CHUNK / TPB)
#define CAP 10240       // bucket region capacity (padded mean ~9360 + slack)
#define RPT (CAP / TPB) // 40 register-cached words per k_sort thread
#define NWAVE (TPB / 64)
#define NSEG 32         // chunk segments for the 2-level offset scan

#if defined(__has_builtin)
#if __has_builtin(__builtin_amdgcn_make_buffer_rsrc) && \
    __has_builtin(__builtin_amdgcn_raw_buffer_load_b128)
#define HAVE_BUFLOAD 1
#endif
#endif

#ifdef HAVE_BUFLOAD
typedef unsigned int u32x4v __attribute__((ext_vector_type(4)));
typedef __amdgpu_buffer_rsrc_t rsrc_t;
__device__ __forceinline__ rsrc_t mkrs(const void* p, int bytes) {
    return __builtin_amdgcn_make_buffer_rsrc(const_cast<void*>(p),
                                             (short)0, bytes, 0x00020000);
}
__device__ __forceinline__ uint4 g16(rsrc_t rs, const uint4* tbl, int idx) {
    u32x4v v = __builtin_amdgcn_raw_buffer_load_b128(rs, idx * 16, 0, 1);
    uint4 q;
    q.x = v.x; q.y = v.y; q.z = v.z; q.w = v.w;
    return q;
}
#else
typedef int rsrc_t;
__device__ __forceinline__ rsrc_t mkrs(const void* p, int bytes) { return 0; }
__device__ __forceinline__ uint4 g16(rsrc_t rs, const uint4* tbl, int idx) {
    return tbl[idx];
}
#endif

__device__ __forceinline__ unsigned short f2bf(float f) {
    unsigned u = __float_as_uint(f);
    unsigned r = (u + 0x7FFFu + ((u >> 16) & 1u)) >> 16;  // RNE
    return (unsigned short)r;
}
__device__ __forceinline__ unsigned pk2(float a, float b) {
    return (unsigned)f2bf(a) | ((unsigned)f2bf(b) << 16);
}
#define BFLO(u) __uint_as_float((u) << 16)
#define BFHI(u) __uint_as_float((u) & 0xFFFF0000u)

// per-chunk bucket histogram -> C[chunk][nb] (coalesced row store)
__global__ void __launch_bounds__(TPB) k_fb1(
        const int* __restrict__ dst, int* __restrict__ C, int e, int nb) {
    __shared__ int h[MAXB];
    int t = threadIdx.x;
    int c0 = blockIdx.x * CHUNK;
    int csize = min(e - c0, CHUNK);
#pragma unroll
    for (int k = 0; k < BPT; k++) h[t * BPT + k] = 0;
    __syncthreads();
    if (csize == CHUNK && ((((size_t)(const void*)(dst + c0)) & 15) == 0)) {
        const int4* d4 = (const int4*)(dst + c0);
#pragma unroll
        for (int k = 0; k < EPT / 4; k++) {
            int4 d = d4[t + k * TPB];
            atomicAdd(&h[d.x >> NBS], 1);
            atomicAdd(&h[d.y >> NBS], 1);
            atomicAdd(&h[d.z >> NBS], 1);
            atomicAdd(&h[d.w >> NBS], 1);
        }
    } else {
        for (int i = t; i < csize; i += TPB)
            atomicAdd(&h[dst[c0 + i] >> NBS], 1);
    }
    __syncthreads();
    int* row = C + (size_t)blockIdx.x * nb;
    for (int b = t; b < nb; b += TPB) row[b] = h[b];
}

// level-1: thread t serially scans bucket-column b over chunk segment s.
// Counts rounded up to multiples of 4 -> every segment start is 16B-aligned.
__global__ void __launch_bounds__(TPB) k_scan1(
        const int* __restrict__ C, int* __restrict__ O, int* __restrict__ Sseg,
        int nchunk, int nb, int cps, int ngrp) {
    int bid = blockIdx.x;
    int s = bid / ngrp, g = bid - s * ngrp;
    int b = g * TPB + threadIdx.x;
    if (b >= nb) return;
    int cbeg = s * cps;
    int cend = min(cbeg + cps, nchunk);
    int run = 0;
#pragma unroll 4
    for (int c = cbeg; c < cend; c++) {
        int v = C[(size_t)c * nb + b];
        O[(size_t)c * nb + b] = run;
        run += (v + 3) & ~3;   // 4-rounded: aligned segments, -1 pad holes
    }
    Sseg[s * nb + b] = run;
}

// level-2: per bucket, exclusive scan of NSEG segment sums; fold in b*CAP.
__global__ void __launch_bounds__(TPB) k_scan2(
        const int* __restrict__ Sseg, int* __restrict__ segbase,
        int* __restrict__ btot, int nb) {
    int b = blockIdx.x * TPB + threadIdx.x;
    if (b >= nb) return;
    int run = b * CAP;
#pragma unroll
    for (int s = 0; s < NSEG; s++) {
        segbase[s * nb + b] = run;
        run += Sseg[s * nb + b];
    }
    btot[b] = run - b * CAP;   // padded bucket total (incl. -1 holes)
}

// bin edges into fixed-cap bucket regions. LDS counting sort of the chunk;
// per-bucket counts read from C (no LDS-atomic histogram); deterministic
// delta from segbase+O; aligned int4 flush. word: ((d&255)<<18)|s
__global__ void __launch_bounds__(TPB) k_fillbin(
        const int* __restrict__ src, const int* __restrict__ dst,
        const int* __restrict__ C, const int* __restrict__ O,
        const int* __restrict__ segbase,
        int* __restrict__ binned, int e, int nb, int cps) {
    __shared__ __align__(16) int stage[CHUNK];  // 32 KB, bucket-sorted words
    __shared__ int h[MAXB];                     // 4 KB, scatter cursor
    __shared__ int wsum[NWAVE];
    int t = threadIdx.x;
    int c0 = blockIdx.x * CHUNK;
    int csize = min(e - c0, CHUNK);
    int dreg[EPT], sreg[EPT];
    if (csize == CHUNK && ((((size_t)(const void*)(dst + c0)) & 15) == 0)
                       && ((((size_t)(const void*)(src + c0)) & 15) == 0)) {
        const int4* d4 = (const int4*)(dst + c0);
        const int4* s4 = (const int4*)(src + c0);
#pragma unroll
        for (int k = 0; k < EPT / 4; k++) {
            int4 d = d4[t + k * TPB];
            int4 s = s4[t + k * TPB];
            dreg[4 * k + 0] = d.x; sreg[4 * k + 0] = s.x;
            dreg[4 * k + 1] = d.y; sreg[4 * k + 1] = s.y;
            dreg[4 * k + 2] = d.z; sreg[4 * k + 2] = s.z;
            dreg[4 * k + 3] = d.w; sreg[4 * k + 3] = s.w;
        }
    } else {
#pragma unroll
        for (int k = 0; k < EPT; k++) {
            int idx = t + k * TPB;
            dreg[k] = (idx < csize) ? dst[c0 + idx] : -1;
            sreg[k] = (idx < csize) ? src[c0 + idx] : 0;
        }
    }
    // per-bucket counts from C row (coalesced; replaces 8192 LDS atomics)
    const int* Crow = C + (size_t)blockIdx.x * nb;
    int loc[BPT], hreg[BPT];
    int ts = 0;
#pragma unroll
    for (int k = 0; k < BPT; k++) {
        int b = t * BPT + k;
        hreg[k] = (b < nb) ? Crow[b] : 0;
        loc[k] = ts;
        ts += hreg[k];
    }
    // block-wide inclusive scan of ts: wave shfl scan + wave-sum combine
    int lane = t & 63, wid = t >> 6;
    int v = ts;
#pragma unroll
    for (int off = 1; off < 64; off <<= 1) {
        int u = __shfl_up(v, off);
        if (lane >= off) v += u;
    }
    if (lane == 63) wsum[wid] = v;
    __syncthreads();
    int pre = 0;
#pragma unroll
    for (int wq = 0; wq < NWAVE - 1; wq++)
        if (wid > wq) pre += wsum[wq];
    int tbase = pre + v - ts;  // exclusive prefix for this thread's first bin
    // deterministic per-bucket dest base (registers; 16B-aligned)
    const int* Orow = O + (size_t)blockIdx.x * nb;
    const int* segrow = segbase + (size_t)(blockIdx.x / cps) * nb;
    int myg[BPT];
#pragma unroll
    for (int k = 0; k < BPT; k++) {
        int b = t * BPT + k;
        int ex = tbase + loc[k];
        h[b] = ex;  // stage cursor (published at next barrier)
        myg[k] = (b < nb) ? (segrow[b] + Orow[b]) : 0;  // 16B-aligned
    }
    __syncthreads();
    // LDS counting sort of the chunk (registers -> LDS only)
#pragma unroll
    for (int k = 0; k < EPT; k++) {
        int d = dreg[k];
        if (d >= 0) {
            int b = d >> NBS;
            int r = atomicAdd(&h[b], 1);
            stage[r] = ((d & (NBKT - 1)) << 18) | sreg[k];
        }
    }
    __syncthreads();
    // per-bucket flush: h[b] is bucket b's END cursor; thread t's buckets
    // [4t,4t+4) occupy one contiguous stage range. Aligned int4 stores,
    // tail padded with -1 up to the 4-rounded segment length.
    int bfirst = t * BPT;
    int s0 = (bfirst == 0) ? 0 : h[bfirst - 1];
#pragma unroll
    for (int k2 = 0; k2 < BPT; k2++) {
        int s1 = h[bfirst + k2];
        int g = myg[k2];  // global aligned start; stage range [s0,s1)
        for (int k = s0; k < s1; k += 4) {
            int4 v4;
            v4.x = stage[k];
            v4.y = (k + 1 < s1) ? stage[k + 1] : -1;
            v4.z = (k + 2 < s1) ? stage[k + 2] : -1;
            v4.w = (k + 3 < s1) ? stage[k + 3] : -1;
            *(int4*)&binned[g + (k - s0)] = v4;
        }
        s0 = s1;
    }
}

// full-bucket counting sort, register-cached (single region read via int4),
// LDS-staged dense csr flush (b128 reads + int4 stores). Pads (w<0) skipped.
__global__ void __launch_bounds__(TPB) k_sort(
        const int* __restrict__ binned, const int* __restrict__ btot,
        const float* __restrict__ x, int* __restrict__ csr,
        int* __restrict__ rowptr, int* __restrict__ rowend,
        float* __restrict__ dinv, uint4* __restrict__ xdq, int n) {
    __shared__ __align__(16) int stage[CAP];     // 40 KB
    __shared__ int cnt[NBKT];
    __shared__ int curs[NBKT];
    __shared__ int wsum[NWAVE];
    int b = blockIdx.x, t = threadIdx.x;
    int base = b * CAP;
    int c = btot[b];
    cnt[t] = 0;
    __syncthreads();
    // 1) read region once into registers (int4) + histogram
    int w[RPT];
#pragma unroll
    for (int k = 0; k < RPT / 4; k++) {
        int idx = 4 * t + k * 4 * TPB;
        int4 v;
        if (idx + 4 <= c) {
            v = *(const int4*)&binned[base + idx];
        } else {
            v.x = (idx + 0 < c) ? binned[base + idx + 0] : -1;
            v.y = (idx + 1 < c) ? binned[base + idx + 1] : -1;
            v.z = (idx + 2 < c) ? binned[base + idx + 2] : -1;
            v.w = (idx + 3 < c) ? binned[base + idx + 3] : -1;
        }
        w[4 * k + 0] = v.x; w[4 * k + 1] = v.y;
        w[4 * k + 2] = v.z; w[4 * k + 3] = v.w;
        if (v.x >= 0) atomicAdd(&cnt[v.x >> 18], 1);
        if (v.y >= 0) atomicAdd(&cnt[v.y >> 18], 1);
        if (v.z >= 0) atomicAdd(&cnt[v.z >> 18], 1);
        if (v.w >= 0) atomicAdd(&cnt[v.w >> 18], 1);
    }
    __syncthreads();
    // 2) exclusive scan of 256 bins: wave shfl scan + combine (1 barrier)
    int v = cnt[t];
    int lane = t & 63, wid = t >> 6;
    int iv = v;
#pragma unroll
    for (int off = 1; off < 64; off <<= 1) {
        int u = __shfl_up(iv, off);
        if (lane >= off) iv += u;
    }
    if (lane == 63) wsum[wid] = iv;
    __syncthreads();
    int pre = 0;
#pragma unroll
    for (int wq = 0; wq < NWAVE - 1; wq++)
        if (wid > wq) pre += wsum[wq];
    int ex = pre + iv - v;  // exclusive (valid edges only; pads excluded)
    curs[t] = ex;
    // 3) per-node outputs
    int i = (b << NBS) + t;
    rowptr[i] = base + ex;
    rowend[i] = base + ex + v;
    if (i < n) {
        float di = rsqrtf((float)(v + 1));
        dinv[i] = di;
        uint4 q;
        q.x = pk2(x[i * 6 + 0] * di, x[i * 6 + 1] * di);
        q.y = pk2(x[i * 6 + 2] * di, x[i * 6 + 3] * di);
        q.z = pk2(x[i * 6 + 4] * di, x[i * 6 + 5] * di);
        q.w = 0;
        xdq[i] = q;
    }
    __syncthreads();
    // 4) scatter from registers into LDS stage (node-sorted order)
#pragma unroll
    for (int k = 0; k < RPT; k++) {
        if (w[k] >= 0) {
            int r = atomicAdd(&curs[w[k] >> 18], 1);
            stage[r] = w[k] & 0x3FFFF;
        }
    }
    __syncthreads();
    // 5) dense flush of valid entries
    int cv = curs[NBKT - 1];   // total valid entries in this bucket
    for (int kb = 4 * t; kb + 4 <= cv; kb += 4 * TPB) {
        int4 sv = *(const int4*)&stage[kb];
        *(int4*)&csr[base + kb] = sv;
    }
    for (int k = (cv & ~3) + t; k < cv; k += TPB)
        csr[base + k] = stage[k];
}

// layer-1 gather (pre-W1 domain, bf16 payload): 16 lanes/node, 4 nodes/wave.
// neighbor payloads via sc0 buffer loads (L1 bypass).
// epilogue: agg6 (incl self) -> @W1 -> relu(di*.+b1) -> @W2 -> *di -> g2q (bf16)
__global__ void __launch_bounds__(TPB) k_gat1(
        const uint4* __restrict__ xdq, const int* __restrict__ csr,
        const int* __restrict__ rowptr, const int* __restrict__ rowend,
        const float* __restrict__ dinv,
        const float* __restrict__ b1, const float* __restrict__ W1,
        const float* __restrict__ W2, uint2* __restrict__ g2q, int n, int np) {
    __shared__ float w1[96];   // 6 x 16
    __shared__ float w2[128];  // 16 x 8
    __shared__ float bb[16];
    if (threadIdx.x < 96) w1[threadIdx.x] = W1[threadIdx.x];
    if (threadIdx.x < 128) w2[threadIdx.x] = W2[threadIdx.x];
    if (threadIdx.x < 16) bb[threadIdx.x] = b1[threadIdx.x];
    __syncthreads();
    rsrc_t rs = mkrs(xdq, np * 16);
    int sub = threadIdx.x & 15;                    // lane within node group
    int i = blockIdx.x * 16 + (threadIdx.x >> 4);  // 16 nodes per block
    bool valid = (i < n);
    int r0 = rowptr[i], r1 = rowend[i];            // padded nodes: r0 == r1
    float a0 = 0.f, a1 = 0.f, a2 = 0.f, a3 = 0.f, a4 = 0.f, a5 = 0.f;
    float c0 = 0.f, c1 = 0.f, c2 = 0.f, c3 = 0.f, c4 = 0.f, c5 = 0.f;
    if (valid && sub == 0) {  // self-loop term
        uint4 q = xdq[i];
        a0 += BFLO(q.x); a1 += BFHI(q.x);
        a2 += BFLO(q.y); a3 += BFHI(q.y);
        a4 += BFLO(q.z); a5 += BFHI(q.z);
    }
    int j = r0 + sub;
    while (j + 16 < r1) {
        uint4 q = g16(rs, xdq, csr[j]);
        uint4 p = g16(rs, xdq, csr[j + 16]);
        a0 += BFLO(q.x); a1 += BFHI(q.x);
        a2 += BFLO(q.y); a3 += BFHI(q.y);
        a4 += BFLO(q.z); a5 += BFHI(q.z);
        c0 += BFLO(p.x); c1 += BFHI(p.x);
        c2 += BFLO(p.y); c3 += BFHI(p.y);
        c4 += BFLO(p.z); c5 += BFHI(p.z);
        j += 32;
    }
    if (j < r1) {
        uint4 q = g16(rs, xdq, csr[j]);
        a0 += BFLO(q.x); a1 += BFHI(q.x);
        a2 += BFLO(q.y); a3 += BFHI(q.y);
        a4 += BFLO(q.z); a5 += BFHI(q.z);
    }
    a0 += c0; a1 += c1; a2 += c2; a3 += c3; a4 += c4; a5 += c5;
#pragma unroll
    for (int m = 1; m <= 8; m <<= 1) {  // reduce within 16-lane node group
        a0 += __shfl_xor(a0, m); a1 += __shfl_xor(a1, m);
        a2 += __shfl_xor(a2, m); a3 += __shfl_xor(a3, m);
        a4 += __shfl_xor(a4, m); a5 += __shfl_xor(a5, m);
    }
    float di = valid ? dinv[i] : 0.f;
    int f = sub;  // lane = hidden feature
    float hf = a0 * w1[f] + a1 * w1[16 + f] + a2 * w1[32 + f]
             + a3 * w1[48 + f] + a4 * w1[64 + f] + a5 * w1[80 + f];
    float tf = fmaxf(di * hf + bb[f], 0.0f);
    float p0 = tf * w2[f * 8 + 0], p1 = tf * w2[f * 8 + 1];
    float p2 = tf * w2[f * 8 + 2], p3 = tf * w2[f * 8 + 3];
    float p4 = tf * w2[f * 8 + 4], p5 = tf * w2[f * 8 + 5];
    float p6 = tf * w2[f * 8 + 6], p7 = tf * w2[f * 8 + 7];
#pragma unroll
    for (int m = 1; m <= 8; m <<= 1) {  // reduce over the 16 f-lanes
        p0 += __shfl_xor(p0, m); p1 += __shfl_xor(p1, m);
        p2 += __shfl_xor(p2, m); p3 += __shfl_xor(p3, m);
        p4 += __shfl_xor(p4, m); p5 += __shfl_xor(p5, m);
        p6 += __shfl_xor(p6, m); p7 += __shfl_xor(p7, m);
    }
    if (valid && sub < 2) {
        float q0 = sub ? p4 : p0, q1 = sub ? p5 : p1;
        float q2 = sub ? p6 : p2, q3 = sub ? p7 : p3;
        uint2 o;
        o.x = pk2(q0 * di, q1 * di);
        o.y = pk2(q2 * di, q3 * di);
        g2q[i * 2 + sub] = o;
    }
}

// layer-2 gather (bf16 payload): 16 lanes/node, 4 nodes/wave, sc0 gathers.
// fused head: h = relu(dinv*agg8 + b2); out = sigmoid(h @ Wfc + bfc)
__global__ void __launch_bounds__(TPB) k_gat2(
        const uint4* __restrict__ g2q, const int* __restrict__ csr,
        const int* __restrict__ rowptr, const int* __restrict__ rowend,
        const float* __restrict__ dinv,
        const float* __restrict__ b2, const float* __restrict__ Wfc,
        const float* __restrict__ bfc, float* __restrict__ out, int n, int np) {
    __shared__ float w[8];
    __shared__ float bb[8];
    __shared__ float bf;
    if (threadIdx.x < 8) { w[threadIdx.x] = Wfc[threadIdx.x]; bb[threadIdx.x] = b2[threadIdx.x]; }
    if (threadIdx.x == 0) bf = bfc[0];
    __syncthreads();
    rsrc_t rs = mkrs(g2q, np * 16);
    int sub = threadIdx.x & 15;
    int i = blockIdx.x * 16 + (threadIdx.x >> 4);
    bool valid = (i < n);
    int r0 = rowptr[i], r1 = rowend[i];
    float a0 = 0.f, a1 = 0.f, a2 = 0.f, a3 = 0.f;
    float a4 = 0.f, a5 = 0.f, a6 = 0.f, a7 = 0.f;
    if (valid && sub == 0) {  // self-loop term
        uint4 q = g2q[i];
        a0 += BFLO(q.x); a1 += BFHI(q.x); a2 += BFLO(q.y); a3 += BFHI(q.y);
        a4 += BFLO(q.z); a5 += BFHI(q.z); a6 += BFLO(q.w); a7 += BFHI(q.w);
    }
    float c0 = 0.f, c1 = 0.f, c2 = 0.f, c3 = 0.f;
    float c4 = 0.f, c5 = 0.f, c6 = 0.f, c7 = 0.f;
    int j = r0 + sub;
    while (j + 16 < r1) {
        uint4 q = g16(rs, g2q, csr[j]);
        uint4 p = g16(rs, g2q, csr[j + 16]);
        a0 += BFLO(q.x); a1 += BFHI(q.x); a2 += BFLO(q.y); a3 += BFHI(q.y);
        a4 += BFLO(q.z); a5 += BFHI(q.z); a6 += BFLO(q.w); a7 += BFHI(q.w);
        c0 += BFLO(p.x); c1 += BFHI(p.x); c2 += BFLO(p.y); c3 += BFHI(p.y);
        c4 += BFLO(p.z); c5 += BFHI(p.z); c6 += BFLO(p.w); c7 += BFHI(p.w);
        j += 32;
    }
    if (j < r1) {
        uint4 q = g16(rs, g2q, csr[j]);
        a0 += BFLO(q.x); a1 += BFHI(q.x); a2 += BFLO(q.y); a3 += BFHI(q.y);
        a4 += BFLO(q.z); a5 += BFHI(q.z); a6 += BFLO(q.w); a7 += BFHI(q.w);
    }
    a0 += c0; a1 += c1; a2 += c2; a3 += c3;
    a4 += c4; a5 += c5; a6 += c6; a7 += c7;
#pragma unroll
    for (int m = 1; m <= 8; m <<= 1) {  // reduce within 16-lane node group
        a0 += __shfl_xor(a0, m); a1 += __shfl_xor(a1, m);
        a2 += __shfl_xor(a2, m); a3 += __shfl_xor(a3, m);
        a4 += __shfl_xor(a4, m); a5 += __shfl_xor(a5, m);
        a6 += __shfl_xor(a6, m); a7 += __shfl_xor(a7, m);
    }
    if (valid && sub == 0) {  // head computed once per node (cheap, no shfl)
        float di = dinv[i];
        float o = bf;
        o += fmaxf(di * a0 + bb[0], 0.0f) * w[0];
        o += fmaxf(di * a1 + bb[1], 0.0f) * w[1];
        o += fmaxf(di * a2 + bb[2], 0.0f) * w[2];
        o += fmaxf(di * a3 + bb[3], 0.0f) * w[3];
        o += fmaxf(di * a4 + bb[4], 0.0f) * w[4];
        o += fmaxf(di * a5 + bb[5], 0.0f) * w[5];
        o += fmaxf(di * a6 + bb[6], 0.0f) * w[6];
        o += fmaxf(di * a7 + bb[7], 0.0f) * w[7];
        out[i] = 1.0f / (1.0f + expf(-o));
    }
}

extern "C" void kernel_launch(void* const* d_in, const int* in_sizes, int n_in,
                              void* d_out, int out_size, void* d_ws, size_t ws_size,
                              hipStream_t stream) {
    const float* x   = (const float*)d_in[0];
    const int*   ei  = (const int*)d_in[1];
    const float* W1  = (const float*)d_in[2];
    const float* b1  = (const float*)d_in[3];
    const float* W2  = (const float*)d_in[4];
    const float* b2  = (const float*)d_in[5];
    const float* Wfc = (const float*)d_in[6];
    const float* bfc = (const float*)d_in[7];
    float* out = (float*)d_out;

    const int n = in_sizes[0] / 6;   // 200000 (<= 262144 for 18-bit packing)
    const int e = in_sizes[1] / 2;   // 6400000
    const int* src = ei;
    const int* dst = ei + e;
    const int nb = (n + NBKT - 1) >> NBS;  // 782
    const size_t np = (size_t)nb << NBS;   // padded node count (200192)
    const int nblk = (e + CHUNK - 1) / CHUNK;  // 782 chunks
    const int cps = (nblk + NSEG - 1) / NSEG;  // chunks per segment (25)
    const int ngrp = (nb + TPB - 1) / TPB;     // bucket groups (4)
    const size_t reg = (size_t)nb * CAP;   // bucket-region total (8.0M words)

    int* C       = (int*)d_ws;                 // nblk * nb
    int* O       = C + (size_t)nblk * nb;      // nblk * nb
    int* Sseg    = O + (size_t)nblk * nb;      // NSEG * MAXB
    int* segbase = Sseg + (size_t)NSEG * MAXB; // NSEG * MAXB
    int* btot    = segbase + (size_t)NSEG * MAXB; // MAXB
    int* binned  = btot + MAXB;                // reg (16B-aligned)
    int* csr     = binned + reg;               // reg
    int* rowptr  = csr + reg;                  // np
    int* rowend  = rowptr + np;                // np
    float* dinv  = (float*)(rowend + np);      // np
    size_t off   = (size_t)((int*)(dinv + np) - (int*)d_ws);
    off = (off + 3) & ~(size_t)3;              // 16B-align the uint4 arrays
    uint4* xdq   = (uint4*)((int*)d_ws + off); // np * 16 B
    uint2* g2q   = (uint2*)(xdq + np);         // np * 16 B

    int gw = (n + 15) / 16;              // node-group blocks (16 nodes/block)
    int npw = (int)np;

    k_fb1<<<nblk, TPB, 0, stream>>>(dst, C, e, nb);
    k_scan1<<<NSEG * ngrp, TPB, 0, stream>>>(C, O, Sseg, nblk, nb, cps, ngrp);
    k_scan2<<<ngrp, TPB, 0, stream>>>(Sseg, segbase, btot, nb);
    k_fillbin<<<nblk, TPB, 0, stream>>>(src, dst, C, O, segbase, binned, e, nb, cps);
    k_sort<<<nb, TPB, 0, stream>>>(binned, btot, x, csr, rowptr, rowend, dinv, xdq, n);
    k_gat1<<<gw, TPB, 0, stream>>>(xdq, csr, rowptr, rowend, dinv, b1, W1, W2,
                                   (uint2*)g2q, n, npw);
    k_gat2<<<gw, TPB, 0, stream>>>((const uint4*)g2q, csr, rowptr, rowend, dinv,
                                   b2, Wfc, bfc, out, n, npw);
}